// Round 6
// baseline (3093.541 us; speedup 1.0000x reference)
//
#include <hip/hip_runtime.h>
#include <cmath>

// Problem constants (match reference)
constexpr int   B        = 4;
constexpr int   P        = 2048;   // P1 == P2
constexpr int   D        = 64;
constexpr float EPS      = 0.1f;
constexpr float THRESH   = 0.1f;
constexpr int   MAX_ITER = 100;

constexpr float LOG2E   = 1.44269504088896340736f;
constexpr float LN2     = 0.69314718055994530942f;
constexpr float SCALE   = LOG2E / EPS;   // natural -> log2 domain, /eps folded in
constexpr float UNSCALE = EPS * LN2;     // inverse

// ws layout (floats): u2s[8192] | v2s[8192] | uo[8192] (fallback) / bar (persist) | err[128]
constexpr int WS_U   = 0;
constexpr int WS_V   = 8192;
constexpr int WS_UO  = 16384;   // fallback-only; persist reuses as barrier region
constexpr int WS_BARX = 16384;  // ~1100 u32 words, zeroed by prep
constexpr int WS_ERR = 24576;
constexpr int WS_FLOATS = 24712;

constexpr int NBLK = 256;    // persistent grid: 1 block/CU
constexpr int NTHR = 1024;   // 16 waves x 2 rows = 32 rows/block

typedef float f32x4 __attribute__((ext_vector_type(4)));   // native 4xVGPR tuple for asm

__device__ __forceinline__ float max4(float4 a) {
    return fmaxf(fmaxf(a.x, a.y), fmaxf(a.z, a.w));
}

// ---- system-scope (cross-XCD coherent, L2-bypassing) access helpers ----
__device__ __forceinline__ float ld_sys_f(const float* p) {
    return __hip_atomic_load((float*)p, __ATOMIC_RELAXED, __HIP_MEMORY_SCOPE_SYSTEM);
}
__device__ __forceinline__ void st_sys_f2(float2* p, float m, float s) {
    union { float2 f; unsigned long long u; } pk;
    pk.f.x = m; pk.f.y = s;
    __hip_atomic_store((unsigned long long*)p, pk.u, __ATOMIC_RELAXED, __HIP_MEMORY_SCOPE_SYSTEM);
}
// 16-byte system-scope ops (sc0 sc1): full-sector writes avoid the 4x sector
// amplification 8-byte stores showed in r2/r3 (proven fix in r5).
__device__ __forceinline__ float4 ld_sys_f4(const float4* p) {
    f32x4 r;
    asm volatile("global_load_dwordx4 %0, %1, off sc0 sc1\n\ts_waitcnt vmcnt(0)"
                 : "=v"(r) : "v"(p) : "memory");
    return make_float4(r.x, r.y, r.z, r.w);
}
__device__ __forceinline__ void st_sys_f4(float4* p, float4 v) {
    f32x4 t;
    t.x = v.x; t.y = v.y; t.z = v.z; t.w = v.w;
    asm volatile("global_store_dwordx4 %0, %1, off sc0 sc1"
                 :: "v"(p), "v"(t) : "memory");
}

// ---- hierarchical fence-free grid barrier (proven r5) ----
// 16 groups x 16 blocks; counters/release 128 B apart; monotonic epochs.
__device__ __forceinline__ void gbar_core(unsigned* bar, unsigned ep) {
    const int g = blockIdx.x & 15;
    unsigned* gc   = bar + g * 32;
    unsigned* root = bar + 512;
    unsigned* rel  = bar + 544 + g * 32;
    unsigned a = __hip_atomic_fetch_add(gc, 1u, __ATOMIC_RELAXED,
                                        __HIP_MEMORY_SCOPE_SYSTEM);
    if (a == ep * 16u - 1u) {                      // last arrival in group
        unsigned r = __hip_atomic_fetch_add(root, 1u, __ATOMIC_RELAXED,
                                            __HIP_MEMORY_SCOPE_SYSTEM);
        if (r == ep * 16u - 1u) {                  // global last
            #pragma unroll
            for (int j = 0; j < 16; ++j)
                __hip_atomic_store(bar + 544 + j * 32, ep, __ATOMIC_RELAXED,
                                   __HIP_MEMORY_SCOPE_SYSTEM);
        }
    }
    while (__hip_atomic_load(rel, __ATOMIC_RELAXED,
                             __HIP_MEMORY_SCOPE_SYSTEM) < ep)
        __builtin_amdgcn_s_sleep(4);
}
__device__ __forceinline__ void gbar(unsigned* bar, unsigned ep) {
    asm volatile("s_waitcnt vmcnt(0)" ::: "memory");   // drain this wave's stores
    __syncthreads();
    if (threadIdx.x == 0) gbar_core(bar, ep);
    __syncthreads();
}
// barrier + leader-side err fetch -> LDS flag (avoids 4096 same-line sys reads)
__device__ __forceinline__ void gbar_err(unsigned* bar, unsigned ep,
                                         const float* errp, float* flag) {
    asm volatile("s_waitcnt vmcnt(0)" ::: "memory");
    __syncthreads();
    if (threadIdx.x == 0) {
        gbar_core(bar, ep);
        *flag = ld_sys_f(errp);
    }
    __syncthreads();
}

__device__ __forceinline__ void lse_merge(float ma, float sa, float mb, float sb,
                                          float& M, float& S) {
    float m2 = fmaxf(ma, mb);
    S = sa * exp2f(ma - m2) + sb * exp2f(mb - m2);
    M = m2;
}

// ============ prep: C = sum_d (x-y)^2, register-tiled; zero scratch ============
__global__ __launch_bounds__(256)
void prep_kernel(const float* __restrict__ x, const float* __restrict__ y,
                 float* __restrict__ out, float* __restrict__ ws)
{
    const int bid = blockIdx.x, tid = threadIdx.x;
    const int bb = bid >> 9, tr = (bid >> 4) & 31, tc = bid & 15;
    const int row0 = tr * 64, col0 = tc * 128;

    if (bid == 0) {
        for (int i = tid; i < WS_FLOATS; i += 256) ws[i] = 0.0f;
        if (tid < B) out[tid] = 0.0f;
    }

    __shared__ float xs[64 * 65];
    __shared__ float ys[128 * 65];
    for (int i = tid; i < 64 * 64; i += 256) {
        int r = i >> 6, d = i & 63;
        xs[r * 65 + d] = x[(size_t)(bb * P + row0 + r) * D + d];
    }
    for (int i = tid; i < 128 * 64; i += 256) {
        int c = i >> 6, d = i & 63;
        ys[c * 65 + d] = y[(size_t)(bb * P + col0 + c) * D + d];
    }
    __syncthreads();

    const int tx = tid & 15, ty = tid >> 4;
    float acc[4][8];
    #pragma unroll
    for (int j = 0; j < 4; ++j)
        #pragma unroll
        for (int i = 0; i < 8; ++i) acc[j][i] = 0.0f;

    #pragma unroll 4
    for (int k = 0; k < 64; ++k) {
        float xa[4], yb[8];
        #pragma unroll
        for (int j = 0; j < 4; ++j) xa[j] = xs[(ty * 4 + j) * 65 + k];
        #pragma unroll
        for (int i = 0; i < 8; ++i) yb[i] = ys[(tx * 8 + i) * 65 + k];
        #pragma unroll
        for (int j = 0; j < 4; ++j)
            #pragma unroll
            for (int i = 0; i < 8; ++i) {
                float d = xa[j] - yb[i];
                acc[j][i] = fmaf(d, d, acc[j][i]);
            }
    }

    float* C_out = out + B + (size_t)B * P * P;
    #pragma unroll
    for (int j = 0; j < 4; ++j) {
        size_t base = (size_t)(bb * P + row0 + ty * 4 + j) * P + col0 + tx * 8;
        float4 a0 = make_float4(acc[j][0], acc[j][1], acc[j][2], acc[j][3]);
        float4 a1 = make_float4(acc[j][4], acc[j][5], acc[j][6], acc[j][7]);
        ((float4*)&C_out[base])[0] = a0;
        ((float4*)&C_out[base])[1] = a1;
    }
}

// ============ persistent kernel v5: 2 rows/wave — c2 fits the 128-VGPR budget ============
// r2/r3/r5 evidence: the compiler pins this kernel family at 128 VGPRs regardless
// of waves_per_eu hints -> a 4-row c2 (128 regs) ALWAYS spills. Design into the
// budget instead: 16 waves x 2 rows (c2 = 64 regs, live-set ~120), 1024-thr
// blocks, 256 blocks (1/CU), 4 waves/EU. Chunks stay 64/batch (same partial
// traffic as r5). Combine: one wave per colpair, lane = chunk (single coalesced
// 16 B sys load + 6-step butterfly).
// partials layout: part4[batch][colpair 1024][chunk 64] float4=(m0,s0,m1,s1)
__global__ __attribute__((amdgpu_flat_work_group_size(NTHR, NTHR),
                          amdgpu_waves_per_eu(4, 4)))
void persist_kernel(const float* C, float4* part4, float* ws, float* out)
{
    float* v2s = ws + WS_V;
    float* err = ws + WS_ERR;
    unsigned* bar = (unsigned*)(ws + WS_BARX);

    const int bid = blockIdx.x, tid = threadIdx.x;
    const int w = tid >> 6, l = tid & 63;
    const int bb = bid >> 6, rc = bid & 63;          // 64 chunks of 32 rows per batch
    const int row0 = rc * 32;
    const int baserow = bb * P + row0 + w * 2;       // wave w owns rows w*2, w*2+1

    __shared__ float4 qm[16][128];                   // 32 KB per-wave m-quarters
    __shared__ float4 qs[16][128];                   // 32 KB per-wave s-quarters
    __shared__ float4 vbuf[512];                     // 8 KB v staging
    __shared__ float  esm[16];
    __shared__ float  dflag;

    const float A = EPS * __logf(1.0f / (float)P + 1e-8f);

    // ---- load C tile ONCE, pre-scaled: c2 = -C/eps*log2e  (64 VGPRs) ----
    float4 c2[2][8];
    #pragma unroll
    for (int j = 0; j < 2; ++j) {
        const float4* Crow = (const float4*)(C + (size_t)(baserow + j) * P);
        #pragma unroll
        for (int k = 0; k < 8; ++k) {
            float4 cc = Crow[l + 64 * k];
            c2[j][k] = make_float4(-SCALE * cc.x, -SCALE * cc.y,
                                   -SCALE * cc.z, -SCALE * cc.w);
        }
    }
    #pragma unroll
    for (int j = 0; j < 2; ++j)
        #pragma unroll
        for (int k = 0; k < 8; ++k)
            asm volatile("" : "+v"(c2[j][k].x), "+v"(c2[j][k].y),
                              "+v"(c2[j][k].z), "+v"(c2[j][k].w));

    float u_old[2] = {0.0f, 0.0f};
    float u2row[2] = {0.0f, 0.0f};
    float4 v4[8];
    unsigned ep = 0;

    for (int t = 0; t < MAX_ITER; ++t) {
        // ---- stage v (16 B sc loads) -> LDS -> regs ----
        if (tid < 512) {
            const float4* vg = (const float4*)(v2s + bb * P);
            vbuf[tid] = ld_sys_f4(&vg[tid]);
        }
        __syncthreads();
        #pragma unroll
        for (int k = 0; k < 8; ++k) v4[k] = vbuf[l + 64 * k];

        // ---- u update per row (exact max-then-sum LSE, all-register) ----
        float dsum = 0.0f;
        #pragma unroll
        for (int j = 0; j < 2; ++j) {
            float m = -1e30f;
            #pragma unroll
            for (int k = 0; k < 8; ++k) {
                float4 tt = make_float4(v4[k].x + c2[j][k].x, v4[k].y + c2[j][k].y,
                                        v4[k].z + c2[j][k].z, v4[k].w + c2[j][k].w);
                m = fmaxf(m, max4(tt));
            }
            #pragma unroll
            for (int off = 1; off < 64; off <<= 1) m = fmaxf(m, __shfl_xor(m, off));
            float s = 0.0f;
            #pragma unroll
            for (int k = 0; k < 8; ++k) {
                s += exp2f(v4[k].x + c2[j][k].x - m) + exp2f(v4[k].y + c2[j][k].y - m)
                   + exp2f(v4[k].z + c2[j][k].z - m) + exp2f(v4[k].w + c2[j][k].w - m);
            }
            #pragma unroll
            for (int off = 1; off < 64; off <<= 1) s += __shfl_xor(s, off);
            float u_nat = A - UNSCALE * (m + log2f(s));
            u2row[j] = u_nat * SCALE;
            dsum += fabsf(u_nat - u_old[j]);
            u_old[j] = u_nat;
        }
        if (l == 0) esm[w] = dsum;

        // ---- v partials: column-quarter pipeline over LDS ----
        #pragma unroll
        for (int q = 0; q < 4; ++q) {
            #pragma unroll
            for (int h = 0; h < 2; ++h) {
                const int k = 2 * q + h;
                float4 t0 = make_float4(u2row[0] + c2[0][k].x, u2row[0] + c2[0][k].y,
                                        u2row[0] + c2[0][k].z, u2row[0] + c2[0][k].w);
                float4 t1 = make_float4(u2row[1] + c2[1][k].x, u2row[1] + c2[1][k].y,
                                        u2row[1] + c2[1][k].z, u2row[1] + c2[1][k].w);
                float4 pm, ps;
                pm.x = fmaxf(t0.x, t1.x); pm.y = fmaxf(t0.y, t1.y);
                pm.z = fmaxf(t0.z, t1.z); pm.w = fmaxf(t0.w, t1.w);
                ps.x = exp2f(t0.x - pm.x) + exp2f(t1.x - pm.x);
                ps.y = exp2f(t0.y - pm.y) + exp2f(t1.y - pm.y);
                ps.z = exp2f(t0.z - pm.z) + exp2f(t1.z - pm.z);
                ps.w = exp2f(t0.w - pm.w) + exp2f(t1.w - pm.w);
                qm[w][l + 64 * h] = pm;
                qs[w][l + 64 * h] = ps;
            }
            __syncthreads();
            if (q == 0 && tid == 0) {
                float e = 0.0f;
                #pragma unroll
                for (int i = 0; i < 16; ++i) e += esm[i];
                atomicAdd(&err[t], e);                 // one RMW per block
            }
            // fold 16 waves: thread pair (p=tid&1) each folds 8 waves of col tid>>1
            {
                const float* qmf = (const float*)qm;
                const float* qsf = (const float*)qs;
                const int col = tid >> 1, p = tid & 1;
                float M = qmf[(p * 8) * 512 + col], S = qsf[(p * 8) * 512 + col];
                #pragma unroll
                for (int ww = 1; ww < 8; ++ww)
                    lse_merge(M, S, qmf[(p * 8 + ww) * 512 + col],
                              qsf[(p * 8 + ww) * 512 + col], M, S);
                // merge the two halves (lane^1), then pair columns (lane^2)
                {
                    float pm = __shfl_xor(M, 1), psv = __shfl_xor(S, 1);
                    lse_merge(M, S, pm, psv, M, S);
                }
                float m1 = __shfl_xor(M, 2), s1 = __shfl_xor(S, 2);
                if ((tid & 3) == 0) {
                    const int cp = 256 * q + (tid >> 2);
                    st_sys_f4(&part4[((size_t)bb * 1024 + cp) * 64 + rc],
                              make_float4(M, S, m1, s1));
                }
            }
            __syncthreads();
        }

        gbar(bar, ++ep);                               // partials visible

        // ---- distributed combine: one wave per colpair, lane = chunk ----
        {
            const int gp  = bid * 16 + w;              // 0..4095 colpairs
            const int bb2 = gp >> 10, cp2 = gp & 1023;
            float4 a = ld_sys_f4(part4 + ((size_t)bb2 * 1024 + cp2) * 64 + l);
            float M0 = a.x, S0 = a.y, M1 = a.z, S1 = a.w;
            #pragma unroll
            for (int off = 32; off >= 1; off >>= 1) {  // fold 64 chunks
                float pm0 = __shfl_xor(M0, off), ps0 = __shfl_xor(S0, off);
                float pm1 = __shfl_xor(M1, off), ps1 = __shfl_xor(S1, off);
                lse_merge(M0, S0, pm0, ps0, M0, S0);
                lse_merge(M1, S1, pm1, ps1, M1, S1);
            }
            if (l == 0) {
                float v0 = (A - UNSCALE * (M0 + log2f(S0))) * SCALE;
                float v1 = (A - UNSCALE * (M1 + log2f(S1))) * SCALE;
                st_sys_f2((float2*)&v2s[bb2 * 2048 + 2 * cp2], v0, v1);
            }
        }

        gbar_err(bar, ++ep, &err[t], &dflag);          // v visible + err -> LDS
        if (dflag < 4.0f * THRESH) break;              // uniform device-side break
    }

    // ---- fused epilogue: pi = exp((u+v-C)/eps), cost = sum pi*C ----
    {
        if (tid < 512) {
            const float4* vg = (const float4*)(v2s + bb * P);
            vbuf[tid] = ld_sys_f4(&vg[tid]);
        }
        __syncthreads();
        #pragma unroll
        for (int k = 0; k < 8; ++k) v4[k] = vbuf[l + 64 * k];

        float* cost = out;
        float* pi   = out + B;
        float lc = 0.0f;
        #pragma unroll
        for (int j = 0; j < 2; ++j) {
            const int r = row0 + w * 2 + j;
            float4* Prow = (float4*)(pi + (size_t)(bb * P + r) * P);
            const float u2 = u2row[j];
            #pragma unroll
            for (int k = 0; k < 8; ++k) {
                float4 p, cc;
                cc.x = -UNSCALE * c2[j][k].x;          // recover C from register copy
                cc.y = -UNSCALE * c2[j][k].y;
                cc.z = -UNSCALE * c2[j][k].z;
                cc.w = -UNSCALE * c2[j][k].w;
                p.x = exp2f(u2 + v4[k].x + c2[j][k].x);
                p.y = exp2f(u2 + v4[k].y + c2[j][k].y);
                p.z = exp2f(u2 + v4[k].z + c2[j][k].z);
                p.w = exp2f(u2 + v4[k].w + c2[j][k].w);
                lc = fmaf(p.x, cc.x, lc); lc = fmaf(p.y, cc.y, lc);
                lc = fmaf(p.z, cc.z, lc); lc = fmaf(p.w, cc.w, lc);
                Prow[l + 64 * k] = p;
            }
        }
        #pragma unroll
        for (int off = 1; off < 64; off <<= 1) lc += __shfl_xor(lc, off);
        __syncthreads();
        if (l == 0) esm[w] = lc;
        __syncthreads();
        if (tid == 0) {
            float e = 0.0f;
            #pragma unroll
            for (int i = 0; i < 16; ++i) e += esm[i];
            atomicAdd(&cost[bb], e);
        }
    }
}

// ============ fallback path (proven multi-kernel, 7704 us) ============
__global__ __launch_bounds__(256, 2)
void iter_kernel(const float* __restrict__ C, float* __restrict__ part_m,
                 float* __restrict__ part_s, float* __restrict__ ws, int t)
{
    float* u2s = ws + WS_U;
    float* v2s = ws + WS_V;
    float* uo  = ws + WS_UO;
    float* err = ws + WS_ERR;
    if (t > 0 && err[t - 1] < 4.0f * THRESH) return;

    const int bid = blockIdx.x, tid = threadIdx.x;
    const int w = tid >> 6, l = tid & 63;
    const int bb = bid >> 7, rc = bid & 127;
    const int row0 = rc * 16;
    const int baserow = bb * P + row0 + w * 4;

    __shared__ float4 m_lds[4 * 512];
    __shared__ float4 s_lds[4 * 512];

    const float A = EPS * __logf(1.0f / (float)P + 1e-8f);

    const float4* vv = (const float4*)(v2s + bb * P);
    float4 v4[8];
    #pragma unroll
    for (int k = 0; k < 8; ++k) v4[k] = vv[l + 64 * k];

    float4 c2[4][8];
    #pragma unroll
    for (int j = 0; j < 4; ++j) {
        const float4* Crow = (const float4*)(C + (size_t)(baserow + j) * P);
        #pragma unroll
        for (int k = 0; k < 8; ++k) {
            float4 cc = Crow[l + 64 * k];
            c2[j][k] = make_float4(-SCALE * cc.x, -SCALE * cc.y,
                                   -SCALE * cc.z, -SCALE * cc.w);
        }
    }

    float u2row[4];
    float dsum = 0.0f;
    #pragma unroll
    for (int j = 0; j < 4; ++j) {
        float m = -1e30f;
        #pragma unroll
        for (int k = 0; k < 8; ++k) {
            float4 tt = make_float4(v4[k].x + c2[j][k].x, v4[k].y + c2[j][k].y,
                                    v4[k].z + c2[j][k].z, v4[k].w + c2[j][k].w);
            m = fmaxf(m, max4(tt));
        }
        #pragma unroll
        for (int off = 1; off < 64; off <<= 1) m = fmaxf(m, __shfl_xor(m, off));
        float s = 0.0f;
        #pragma unroll
        for (int k = 0; k < 8; ++k) {
            s += exp2f(v4[k].x + c2[j][k].x - m) + exp2f(v4[k].y + c2[j][k].y - m)
               + exp2f(v4[k].z + c2[j][k].z - m) + exp2f(v4[k].w + c2[j][k].w - m);
        }
        #pragma unroll
        for (int off = 1; off < 64; off <<= 1) s += __shfl_xor(s, off);
        float u_nat = A - UNSCALE * (m + log2f(s));
        u2row[j] = u_nat * SCALE;
        if (l == 0) {
            const int rg = baserow + j;
            dsum += fabsf(u_nat - uo[rg]);
            uo[rg]  = u_nat;
            u2s[rg] = u2row[j];
        }
    }
    if (l == 0) atomicAdd(&err[t], dsum);

    #pragma unroll
    for (int k = 0; k < 8; ++k) {
        float4 t0 = make_float4(u2row[0] + c2[0][k].x, u2row[0] + c2[0][k].y,
                                u2row[0] + c2[0][k].z, u2row[0] + c2[0][k].w);
        float4 t1 = make_float4(u2row[1] + c2[1][k].x, u2row[1] + c2[1][k].y,
                                u2row[1] + c2[1][k].z, u2row[1] + c2[1][k].w);
        float4 t2 = make_float4(u2row[2] + c2[2][k].x, u2row[2] + c2[2][k].y,
                                u2row[2] + c2[2][k].z, u2row[2] + c2[2][k].w);
        float4 t3 = make_float4(u2row[3] + c2[3][k].x, u2row[3] + c2[3][k].y,
                                u2row[3] + c2[3][k].z, u2row[3] + c2[3][k].w);
        float4 pm, ps;
        pm.x = fmaxf(fmaxf(t0.x, t1.x), fmaxf(t2.x, t3.x));
        pm.y = fmaxf(fmaxf(t0.y, t1.y), fmaxf(t2.y, t3.y));
        pm.z = fmaxf(fmaxf(t0.z, t1.z), fmaxf(t2.z, t3.z));
        pm.w = fmaxf(fmaxf(t0.w, t1.w), fmaxf(t2.w, t3.w));
        ps.x = exp2f(t0.x - pm.x) + exp2f(t1.x - pm.x) + exp2f(t2.x - pm.x) + exp2f(t3.x - pm.x);
        ps.y = exp2f(t0.y - pm.y) + exp2f(t1.y - pm.y) + exp2f(t2.y - pm.y) + exp2f(t3.y - pm.y);
        ps.z = exp2f(t0.z - pm.z) + exp2f(t1.z - pm.z) + exp2f(t2.z - pm.z) + exp2f(t3.z - pm.z);
        ps.w = exp2f(t0.w - pm.w) + exp2f(t1.w - pm.w) + exp2f(t2.w - pm.w) + exp2f(t3.w - pm.w);
        m_lds[w * 512 + l + 64 * k] = pm;
        s_lds[w * 512 + l + 64 * k] = ps;
    }
    __syncthreads();

    float4* pm_out = ((float4*)part_m) + (size_t)bid * 512;
    float4* ps_out = ((float4*)part_s) + (size_t)bid * 512;
    #pragma unroll
    for (int h = 0; h < 2; ++h) {
        const int idx = tid * 2 + h;
        float4 M = m_lds[idx], S = s_lds[idx];
        #pragma unroll
        for (int q = 1; q < 4; ++q) {
            float4 pm = m_lds[q * 512 + idx], ps = s_lds[q * 512 + idx];
            float m2;
            m2 = fmaxf(M.x, pm.x); S.x = S.x * exp2f(M.x - m2) + ps.x * exp2f(pm.x - m2); M.x = m2;
            m2 = fmaxf(M.y, pm.y); S.y = S.y * exp2f(M.y - m2) + ps.y * exp2f(pm.y - m2); M.y = m2;
            m2 = fmaxf(M.z, pm.z); S.z = S.z * exp2f(M.z - m2) + ps.z * exp2f(pm.z - m2); M.z = m2;
            m2 = fmaxf(M.w, pm.w); S.w = S.w * exp2f(M.w - m2) + ps.w * exp2f(pm.w - m2); M.w = m2;
        }
        pm_out[idx] = M;
        ps_out[idx] = S;
    }
}

__global__ __launch_bounds__(256)
void comb_kernel(const float* __restrict__ part_m, const float* __restrict__ part_s,
                 float* __restrict__ ws, int t)
{
    float* v2s = ws + WS_V;
    float* err = ws + WS_ERR;
    if (t > 0 && err[t - 1] < 4.0f * THRESH) return;

    const int g = blockIdx.x * 256 + threadIdx.x;
    const int b = g >> 11, c = g & (P - 1);
    const float* pmb = part_m + (size_t)(b * 128) * P + c;
    const float* psb = part_s + (size_t)(b * 128) * P + c;

    const float A = EPS * __logf(1.0f / (float)P + 1e-8f);

    float M = -1e30f;
    #pragma unroll 8
    for (int q = 0; q < 128; ++q) M = fmaxf(M, pmb[(size_t)q * P]);
    float S = 0.0f;
    #pragma unroll 8
    for (int q = 0; q < 128; ++q)
        S = fmaf(psb[(size_t)q * P], exp2f(pmb[(size_t)q * P] - M), S);

    float v_nat = A - UNSCALE * (M + log2f(S));
    v2s[g] = v_nat * SCALE;
}

__global__ __launch_bounds__(256)
void epi_kernel(float* __restrict__ out, const float* __restrict__ ws)
{
    const float* u2s = ws + WS_U;
    const float* v2s = ws + WS_V;
    float* cost = out;
    float* pi   = out + B;
    const float* C = out + B + (size_t)B * P * P;

    const int bid = blockIdx.x, tid = threadIdx.x;
    const int w = tid >> 6, l = tid & 63;
    const int bb = bid >> 7, rc = bid & 127;
    const int row0 = rc * 16;

    const float4* vv = (const float4*)(v2s + bb * P);
    float4 v4[8];
    #pragma unroll
    for (int k = 0; k < 8; ++k) v4[k] = vv[l + 64 * k];

    float lc = 0.0f;
    #pragma unroll
    for (int j = 0; j < 4; ++j) {
        const int r = row0 + w * 4 + j;
        const float u2 = u2s[bb * P + r];
        const float4* Crow = (const float4*)(C  + (size_t)(bb * P + r) * P);
        float4*       Prow = (float4*)      (pi + (size_t)(bb * P + r) * P);
        #pragma unroll
        for (int k = 0; k < 8; ++k) {
            float4 cc = Crow[l + 64 * k];
            float4 p;
            p.x = exp2f(u2 + v4[k].x - SCALE * cc.x);
            p.y = exp2f(u2 + v4[k].y - SCALE * cc.y);
            p.z = exp2f(u2 + v4[k].z - SCALE * cc.z);
            p.w = exp2f(u2 + v4[k].w - SCALE * cc.w);
            lc = fmaf(p.x, cc.x, lc); lc = fmaf(p.y, cc.y, lc);
            lc = fmaf(p.z, cc.z, lc); lc = fmaf(p.w, cc.w, lc);
            Prow[l + 64 * k] = p;
        }
    }
    #pragma unroll
    for (int off = 1; off < 64; off <<= 1) lc += __shfl_xor(lc, off);
    __shared__ float sm[4];
    if (l == 0) sm[w] = lc;
    __syncthreads();
    if (tid == 0) atomicAdd(&cost[bb], sm[0] + sm[1] + sm[2] + sm[3]);
}

extern "C" void kernel_launch(void* const* d_in, const int* in_sizes, int n_in,
                              void* d_out, int out_size, void* d_ws, size_t ws_size,
                              hipStream_t stream) {
    const float* x = (const float*)d_in[0];
    const float* y = (const float*)d_in[1];
    float* out = (float*)d_out;
    float* ws  = (float*)d_ws;
    const float* C = out + B + (size_t)B * P * P;
    // persist partials: [batch][colpair 1024][chunk 64] float4 = 4 MB, in pi region
    float4* part4 = (float4*)(out + B);
    // fallback partials (same region, old layout)
    float* part_m = out + B;
    float* part_s = part_m + 512 * P;

    prep_kernel<<<2048, 256, 0, stream>>>(x, y, out, ws);

    void* args[] = { (void*)&C, (void*)&part4, (void*)&ws, (void*)&out };
    hipError_t e = hipLaunchCooperativeKernel((void*)persist_kernel,
                                              dim3(NBLK), dim3(NTHR),
                                              args, 0, stream);
    if (e != hipSuccess) {
        for (int t = 0; t < MAX_ITER; ++t) {
            iter_kernel<<<512, 256, 0, stream>>>(C, part_m, part_s, ws, t);
            comb_kernel<<<32,  256, 0, stream>>>(part_m, part_s, ws, t);
        }
        epi_kernel<<<512, 256, 0, stream>>>(out, ws);
    }
}